// Round 4
// baseline (80.768 us; speedup 1.0000x reference)
//
#include <hip/hip_runtime.h>
#include <math.h>

// SSIM loss, fused separable implementation, round 4.
// Algebra: s=x+y, d=x-y; 4 separable Gaussian convs (s, d, s^2, d^2):
//   2*mu1mu2 = (mp^2-mm^2)/2 ; mu1^2+mu2^2 = (mp^2+mm^2)/2
//   2*s12    = (varP-varM)/2 ; s11+s22    = (varP+varM)/2
// Round-4 changes vs round 3 (105us, VALUBusy 48%):
//  - double-buffered LDS, CH=4 (same 67584B footprint), ONE barrier per chunk:
//    body = [H(c) reads buf(c&1) | V(c+1) writes buf(~c&1) | prefetch | lgkm | bar].
//    H's LDS latency overlaps V's independent packed FMAs in one barrier-free
//    window; waves no longer lockstep at 2 barriers/chunk.
//  - precomputed horizontal read offsets va[14] (clamp+swizzle hoisted out of
//    the per-chunk loop; they depend only on tid).

#define HH 512
#define WW 512
#define NPLANES 96   // 32*3
#define ROWS 64      // output rows per block
#define CH 4         // chunk rows per barrier period
#define NCHUNK 16
#define LSTRIDE 528  // float4 slots per row: 8 zero-guard + 512 + 8 zero-guard
#define BUFSZ (CH * LSTRIDE)
#define NT 512

#define C1F 0.0001f  // 0.01^2
#define C2F 0.0009f  // 0.03^2

typedef float f32x2 __attribute__((ext_vector_type(2)));

__device__ __forceinline__ int swz(int c) { return c ^ ((c >> 5) & 31); }
__device__ __forceinline__ f32x2 fma2(f32x2 a, f32x2 b, f32x2 c) {
  return __builtin_elementwise_fma(a, b, c);
}

extern "C" __global__ __launch_bounds__(NT, 2)
void ssim_main(const float* __restrict__ Ii, const float* __restrict__ Ir,
               const float* __restrict__ win, float* __restrict__ partial) {
  __shared__ float4 vbuf[2 * BUFSZ];   // 2*4*528*16B = 67584 B
  __shared__ float psum[8];

  const int tid = threadIdx.x;
  const int b = blockIdx.x;
  const int plane = b >> 3;
  const int r0 = (b & 7) * ROWS;

  // 1-D gaussian from the 2-D window (wave-uniform)
  float g[11];
  {
    float gi = 1.0f / sqrtf(win[55 + 5]);
#pragma unroll
    for (int j = 0; j < 11; ++j) g[j] = win[55 + j] * gi;
  }

  const size_t pbase = (size_t)plane * (HH * WW) + tid;
  const float* pA = Ii + pbase;   // this thread's column
  const float* pB = Ir + pbase;
  const int wb = 8 + swz(tid);    // swizzled LDS write slot

  // zero guard slots of both buffers once (2 bufs * 4 rows * 16 slots = 128)
  if (tid < 128) {
    const int bufo = (tid >> 6) * BUFSZ, t = tid & 63, lr = t >> 4, p = t & 15;
    vbuf[bufo + lr * LSTRIDE + (p < 8 ? p : 512 + p)] = make_float4(0.f, 0.f, 0.f, 0.f);
  }

  // precomputed horizontal read offsets (per-thread constants)
  const int hrow = tid >> 7;           // 0..3
  const int c0 = (tid & 127) * 4;      // 4 output cols per thread
  int va[14];
#pragma unroll
  for (int j = 0; j < 14; ++j) {
    const int col = c0 + j - 5;
    va[j] = hrow * LSTRIDE + 8 + (((unsigned)col > 511u) ? col : swz(col));
  }

  // mod-11 ring accumulators, packed: r1=(S,D), r2=(P,M); static indices only
  f32x2 r1[11], r2[11];
  float pfA[CH], pfB[CH];
  float sum = 0.f;

  auto loadrow = [&](int u, float& a, float& bb) {
    const int r = r0 - 5 + u;
    const int rc = min(max(r, 0), HH - 1);
    float ta = pA[(size_t)rc * WW];
    float tb = pB[(size_t)rc * WW];
    const bool ok = (unsigned)r < (unsigned)HH;
    a = ok ? ta : 0.f;
    bb = ok ? tb : 0.f;
  };

  // vertical step for input local row u (compile-time); emit to lr when lr>=0
  auto vrow = [&](int u, float a, float bb, int lr, int bufo) {
    f32x2 sd; sd.x = a + bb; sd.y = a - bb;
    const f32x2 pm = sd * sd;
    {
      const int sl = u % 11;
      f32x2 w2; w2.x = g[0]; w2.y = g[0];
      r1[sl] = w2 * sd;
      r2[sl] = w2 * pm;
    }
#pragma unroll
    for (int t = 1; t < 11; ++t) {
      const int sl = (u + 44 - t) % 11;
      f32x2 w2; w2.x = g[t]; w2.y = g[t];
      r1[sl] = fma2(w2, sd, r1[sl]);
      r2[sl] = fma2(w2, pm, r2[sl]);
    }
    if (lr >= 0) {
      const int sl = (u + 1) % 11;     // (u-10) mod 11
      const f32x2 a1 = r1[sl], a2 = r2[sl];
      vbuf[bufo + lr * LSTRIDE + wb] = make_float4(a1.x, a1.y, a2.x, a2.y);
    }
  };

  // horizontal conv + SSIM for the CH rows in buf at bufo
  auto hchunk = [&](int bufo) {
    f32x2 h01[4], h23[4];
#pragma unroll
    for (int j = 0; j < 14; ++j) {
      const float4 v = vbuf[bufo + va[j]];
      f32x2 v01; v01.x = v.x; v01.y = v.y;
      f32x2 v23; v23.x = v.z; v23.y = v.w;
      const int clo = (j - 10 > 0) ? (j - 10) : 0;
      const int chi = (j < 3) ? j : 3;
#pragma unroll
      for (int c = clo; c <= chi; ++c) {
        f32x2 w2; w2.x = g[j - c]; w2.y = g[j - c];
        if (c == j) { h01[c] = w2 * v01;              h23[c] = w2 * v23; }
        else        { h01[c] = fma2(w2, v01, h01[c]); h23[c] = fma2(w2, v23, h23[c]); }
      }
    }
#pragma unroll
    for (int c = 0; c < 4; ++c) {
      const f32x2 m2 = h01[c] * h01[c];     // (mp^2, mm^2)
      const f32x2 var = h23[c] - m2;        // (varP, varM)
      const float num1 = 0.5f * (m2.x - m2.y) + C1F;
      const float den1 = 0.5f * (m2.x + m2.y) + C1F;
      const float num2 = 0.5f * (var.x - var.y) + C2F;
      const float den2 = 0.5f * (var.x + var.y) + C2F;
      sum += __fdividef(num1 * num2, den1 * den2);
    }
  };

  // prologue: ring fill (u=0..9), V(0)->buf0 (u=10..13), prefetch chunk 1
#pragma unroll
  for (int u = 0; u < 10; ++u) {
    float a, bb; loadrow(u, a, bb); vrow(u, a, bb, -1, 0);
  }
#pragma unroll
  for (int i = 0; i < CH; ++i) loadrow(10 + i, pfA[i], pfB[i]);
#pragma unroll
  for (int i = 0; i < CH; ++i) vrow(10 + i, pfA[i], pfB[i], i, 0);
#pragma unroll
  for (int i = 0; i < CH; ++i) loadrow(14 + i, pfA[i], pfB[i]);
  asm volatile("s_waitcnt lgkmcnt(0)" ::: "memory");
  __builtin_amdgcn_s_barrier();

  // main: one barrier per chunk; H(c) | V(c+1) | prefetch(c+2) share a window
#pragma unroll
  for (int c = 0; c < NCHUNK; ++c) {
    hchunk((c & 1) * BUFSZ);
    if (c < NCHUNK - 1) {
#pragma unroll
      for (int i = 0; i < CH; ++i)
        vrow(14 + 4 * c + i, pfA[i], pfB[i], i, ((c + 1) & 1) * BUFSZ);
      if (c < NCHUNK - 2) {
#pragma unroll
        for (int i = 0; i < CH; ++i) loadrow(18 + 4 * c + i, pfA[i], pfB[i]);
      }
      asm volatile("s_waitcnt lgkmcnt(0)" ::: "memory");
      __builtin_amdgcn_s_barrier();
    }
  }

  // deterministic block reduction
#pragma unroll
  for (int off = 32; off > 0; off >>= 1) sum += __shfl_down(sum, off, 64);
  if ((tid & 63) == 0) psum[tid >> 6] = sum;
  __syncthreads();
  if (tid == 0) {
    float t = 0.f;
#pragma unroll
    for (int wv = 0; wv < 8; ++wv) t += psum[wv];
    partial[b] = t;
  }
}

extern "C" __global__ void ssim_reduce(const float* __restrict__ partial,
                                       float* __restrict__ out, int n, float scale) {
  __shared__ float sm[4];
  const int tid = threadIdx.x;
  float v = 0.f;
  for (int i = tid; i < n; i += 256) v += partial[i];
#pragma unroll
  for (int off = 32; off > 0; off >>= 1) v += __shfl_down(v, off, 64);
  if ((tid & 63) == 0) sm[tid >> 6] = v;
  __syncthreads();
  if (tid == 0) {
    out[0] = 1.0f - (sm[0] + sm[1] + sm[2] + sm[3]) * scale;
  }
}

extern "C" void kernel_launch(void* const* d_in, const int* in_sizes, int n_in,
                              void* d_out, int out_size, void* d_ws, size_t ws_size,
                              hipStream_t stream) {
  const float* Ii = (const float*)d_in[0];
  const float* Ir = (const float*)d_in[1];
  const float* win = (const float*)d_in[2];
  float* out = (float*)d_out;
  float* partial = (float*)d_ws;   // 768 floats

  const int nblocks = NPLANES * 8;  // 768
  ssim_main<<<dim3(nblocks), dim3(NT), 0, stream>>>(Ii, Ir, win, partial);
  ssim_reduce<<<dim3(1), dim3(256), 0, stream>>>(partial, out, nblocks,
                                                 1.0f / 25165824.0f);
}